// Round 10
// baseline (209.086 us; speedup 1.0000x reference)
//
#include <hip/hip_runtime.h>

// Guided filter r=8 (K=17), eps=0.1, (8,3,1024,1024); inputs F32, output F32.
// (Dtypes pinned by R8's NaN [inputs=f32] and R9's 0.578 garbage [output=f32].)
// Fused single kernel, zero workspace, defensive indexing.
//
// Per 32x32 output tile (256-thread block), one reused LDS arena of 4 planes
// [48 rows][stride 67]:
//   A : vertical 17-tap sliding sums of {I,p,I*p,I*I} read directly from
//       global (running re-read sums) -> planes 0..3.
//       vs row v in [0,48) ~ img row ty0+v-8; vs col c in [0,64) ~ img col tx0+c-16
//   B1: horizontal 17-tap sums -> a,b in 12 regs/thread, barrier,
//       write a,b over dead planes 0,1 (region 48x48)
//   B2: horizontal 17-tap sums of a,b -> planes 2,3 (48 x 32)
//   C : vertical 17-tap sums + out = mean_a*I + mean_b  (f32 store)

#define TW 32
#define TH 32
#define STRD 67
#define VROWS 48
#define PL (VROWS * STRD)          // 3216 floats per plane
#define INV_AREA (1.0f / 289.0f)
#define EPS 0.1f

__device__ __forceinline__ int refl1024(int v) {
    v = (v < 0) ? -v : v;
    v = (v > 1023) ? 2046 - v : v;
    if (v < 0) v = 0;              // defensive clamp
    if (v > 1023) v = 1023;
    return v;
}

__global__ __launch_bounds__(256) void gf_fused(
    const float* __restrict__ P, const float* __restrict__ I,
    float* __restrict__ O, int H, int W)
{
    __shared__ float S[4 * PL];    // 51456 B

    const int tid = threadIdx.x;
    const int tx0 = blockIdx.x * TW;
    const int ty0 = blockIdx.y * TH;
    const size_t plane = (size_t)blockIdx.z * H * W;
    const float* __restrict__ Ic = I + plane;
    const float* __restrict__ Pc = P + plane;

    // ---------------- Phase A: vertical sliding sums (global -> LDS) --------
    {
        const int vc = tid & 63;            // vs col 0..63
        const int r0 = (tid >> 6) * 12;     // row chunk base: 0,12,24,36
        const int gx = refl1024(tx0 + vc - 16);
        float s0 = 0.f, s1 = 0.f, s2 = 0.f, s3 = 0.f;
        #pragma unroll
        for (int j = 0; j < 17; ++j) {
            const int gy = refl1024(ty0 + r0 - 16 + j);
            const float a = Ic[(size_t)gy * W + gx];
            const float b = Pc[(size_t)gy * W + gx];
            s0 += a; s1 += b; s2 += a * b; s3 += a * a;
        }
        S[0 * PL + r0 * STRD + vc] = s0;
        S[1 * PL + r0 * STRD + vc] = s1;
        S[2 * PL + r0 * STRD + vc] = s2;
        S[3 * PL + r0 * STRD + vc] = s3;
        #pragma unroll
        for (int o = 1; o < 12; ++o) {
            const int gyN = refl1024(ty0 + r0 + o);        // add row
            const int gyO = refl1024(ty0 + r0 + o - 17);   // drop row
            const float an = Ic[(size_t)gyN * W + gx];
            const float bn = Pc[(size_t)gyN * W + gx];
            const float ao = Ic[(size_t)gyO * W + gx];
            const float bo = Pc[(size_t)gyO * W + gx];
            s0 += an - ao;
            s1 += bn - bo;
            s2 += an * bn - ao * bo;
            s3 += an * an - ao * ao;
            S[0 * PL + (r0 + o) * STRD + vc] = s0;
            S[1 * PL + (r0 + o) * STRD + vc] = s1;
            S[2 * PL + (r0 + o) * STRD + vc] = s2;
            S[3 * PL + (r0 + o) * STRD + vc] = s3;
        }
    }
    __syncthreads();

    // ---------------- Phase B1: horizontal sums -> a,b ----------------------
    const int vr  = tid >> 2;          // 0..47 (tid<192)
    const int u12 = (tid & 3) * 12;    // ab col base 0,12,24,36
    float oa[12], ob[12];
    if (tid < 192) {
        float s0 = 0.f, s1 = 0.f, s2 = 0.f, s3 = 0.f;
        #pragma unroll
        for (int j = 0; j < 17; ++j) {
            const int ix = vr * STRD + u12 + j;
            s0 += S[0 * PL + ix];
            s1 += S[1 * PL + ix];
            s2 += S[2 * PL + ix];
            s3 += S[3 * PL + ix];
        }
        #pragma unroll
        for (int o = 0; o < 12; ++o) {
            if (o) {
                const int iN = vr * STRD + u12 + o + 16;
                const int iO = vr * STRD + u12 + o - 1;
                s0 += S[0 * PL + iN] - S[0 * PL + iO];
                s1 += S[1 * PL + iN] - S[1 * PL + iO];
                s2 += S[2 * PL + iN] - S[2 * PL + iO];
                s3 += S[3 * PL + iN] - S[3 * PL + iO];
            }
            const float mI  = s0 * INV_AREA;
            const float mP  = s1 * INV_AREA;
            const float mIp = s2 * INV_AREA;
            const float mII = s3 * INV_AREA;
            const float cov = mIp - mI * mP;
            const float var = mII - mI * mI;
            const float av  = cov / (var + EPS);
            oa[o] = av;
            ob[o] = mP - av * mI;
        }
    }
    __syncthreads();
    if (tid < 192) {
        #pragma unroll
        for (int o = 0; o < 12; ++o) {
            S[0 * PL + vr * STRD + u12 + o] = oa[o];
            S[1 * PL + vr * STRD + u12 + o] = ob[o];
        }
    }
    __syncthreads();

    // ---------------- Phase B2: horizontal sums of a,b -> planes 2,3 --------
    if (tid < 192) {
        const int w8 = (tid & 3) * 8;      // hs col base 0,8,16,24
        float sa = 0.f, sb = 0.f;
        #pragma unroll
        for (int j = 0; j < 17; ++j) {
            const int ix = vr * STRD + w8 + j;
            sa += S[0 * PL + ix];
            sb += S[1 * PL + ix];
        }
        #pragma unroll
        for (int o = 0; o < 8; ++o) {
            if (o) {
                const int iN = vr * STRD + w8 + o + 16;
                const int iO = vr * STRD + w8 + o - 1;
                sa += S[0 * PL + iN] - S[0 * PL + iO];
                sb += S[1 * PL + iN] - S[1 * PL + iO];
            }
            S[2 * PL + vr * STRD + w8 + o] = sa;
            S[3 * PL + vr * STRD + w8 + o] = sb;
        }
    }
    __syncthreads();

    // ---------------- Phase C: vertical sums + finale (f32 store) -----------
    {
        const int ox  = tid & 31;
        const int oy0 = (tid >> 5) * 4;    // 0,4,...,28
        float sa = 0.f, sb = 0.f;
        #pragma unroll
        for (int j = 0; j < 17; ++j) {
            sa += S[2 * PL + (oy0 + j) * STRD + ox];
            sb += S[3 * PL + (oy0 + j) * STRD + ox];
        }
        #pragma unroll
        for (int o = 0; o < 4; ++o) {
            if (o) {
                sa += S[2 * PL + (oy0 + o + 16) * STRD + ox]
                    - S[2 * PL + (oy0 + o - 1) * STRD + ox];
                sb += S[3 * PL + (oy0 + o + 16) * STRD + ox]
                    - S[3 * PL + (oy0 + o - 1) * STRD + ox];
            }
            const size_t g = plane + (size_t)(ty0 + oy0 + o) * W + (tx0 + ox);
            O[g] = sa * INV_AREA * Ic[(size_t)(ty0 + oy0 + o) * W + (tx0 + ox)]
                 + sb * INV_AREA;
        }
    }
}

extern "C" void kernel_launch(void* const* d_in, const int* in_sizes, int n_in,
                              void* d_out, int out_size, void* d_ws, size_t ws_size,
                              hipStream_t stream) {
    const int H = 1024, W = 1024;
    if (n_in < 2) return;
    const long long npx = (long long)H * W;
    const long long n0 = in_sizes[0];
    if (n0 <= 0 || (n0 % npx) != 0) return;
    if ((long long)out_size != n0) return;
    if (in_sizes[1] != in_sizes[0]) return;
    const int NP = (int)(n0 / npx);

    const float* p = (const float*)d_in[0];   // input_img
    const float* I = (const float*)d_in[1];   // guide_img
    float* out = (float*)d_out;

    dim3 grid(W / TW, H / TH, NP);
    gf_fused<<<grid, 256, 0, stream>>>(p, I, out, H, W);
}

// Round 11
// 196.088 us; speedup vs baseline: 1.0663x; 1.0663x over previous
//
#include <hip/hip_runtime.h>

// Guided filter r=8 (K=17), eps=0.1, (8,3,1024,1024); f32 in / f32 out.
// Fused single kernel, zero workspace. V2: vectorized LDS (b128), register
// window in phase A, scalar-hoisted row addresses.
//
// Per 32x32 output tile (256-thread block), LDS arena = 4 planes [48][68] f32
// (stride 68 words = 272 B, 16B-aligned rows; 52224 B total, 3 blocks/CU):
//   A : vertical 17-tap sliding sums of {I,p,I*p,I*I}; 28-row register
//       window per thread (64 cols x 4 row-chunks of 12) -> planes 0..3
//   B1: horizontal 17-tap sums via ds_read_b128 (7 f4 per plane) -> a,b;
//       barrier; write a,b over planes 0,1 as 3+3 ds_write_b128
//   B2: horizontal 17-tap sums of a,b (6+6 f4 reads) -> planes 2,3 (2+2 f4 w)
//   C : vertical 17-tap sliding sums of hs (b32, conflict-free) + finale

#define TW 32
#define TH 32
#define STRD 68                    // words; 272 B rows
#define VROWS 48
#define PL (VROWS * STRD)          // 3264 words/plane
#define PL4 (PL / 4)               // 816 float4/plane
#define INV_AREA (1.0f / 289.0f)
#define EPS 0.1f

__device__ __forceinline__ int refl1024(int v) {
    v = (v < 0) ? -v : v;
    v = (v > 1023) ? 2046 - v : v;
    if (v < 0) v = 0;
    if (v > 1023) v = 1023;
    return v;
}

__global__ __launch_bounds__(256) void gf_fused(
    const float* __restrict__ P, const float* __restrict__ I,
    float* __restrict__ O, int H, int W)
{
    __shared__ __align__(16) float4 S4[4 * PL4];   // 52224 B
    float* __restrict__ Sf = (float*)S4;

    const int tid = threadIdx.x;
    const int tx0 = blockIdx.x * TW;
    const int ty0 = blockIdx.y * TH;
    const size_t plane = (size_t)blockIdx.z * H * W;
    const float* __restrict__ Ic = I + plane;
    const float* __restrict__ Pc = P + plane;

    // ---------------- Phase A: vertical sliding sums ------------------------
    {
        const int vc = tid & 63;                                   // vs col
        const int ck = __builtin_amdgcn_readfirstlane(tid >> 6);   // wave-uniform
        const int r0 = ck * 12;
        const int gx = refl1024(tx0 + vc - 16);

        float vI[28], vP[28];
        #pragma unroll
        for (int j = 0; j < 28; ++j) {
            const int gy = refl1024(ty0 + r0 - 16 + j);            // scalar
            const float* __restrict__ rI = Ic + (size_t)gy * W;    // SGPR base
            const float* __restrict__ rP = Pc + (size_t)gy * W;
            vI[j] = rI[gx];
            vP[j] = rP[gx];
        }
        float s0 = 0.f, s1 = 0.f, s2 = 0.f, s3 = 0.f;
        #pragma unroll
        for (int j = 0; j < 17; ++j) {
            s0 += vI[j]; s1 += vP[j];
            s2 += vI[j] * vP[j];
            s3 += vI[j] * vI[j];
        }
        Sf[0 * PL + r0 * STRD + vc] = s0;
        Sf[1 * PL + r0 * STRD + vc] = s1;
        Sf[2 * PL + r0 * STRD + vc] = s2;
        Sf[3 * PL + r0 * STRD + vc] = s3;
        #pragma unroll
        for (int o = 1; o < 12; ++o) {
            const float ni = vI[o + 16], oi = vI[o - 1];
            const float np_ = vP[o + 16], op_ = vP[o - 1];
            s0 += ni - oi;
            s1 += np_ - op_;
            s2 += ni * np_ - oi * op_;
            s3 += ni * ni - oi * oi;
            Sf[0 * PL + (r0 + o) * STRD + vc] = s0;
            Sf[1 * PL + (r0 + o) * STRD + vc] = s1;
            Sf[2 * PL + (r0 + o) * STRD + vc] = s2;
            Sf[3 * PL + (r0 + o) * STRD + vc] = s3;
        }
    }
    __syncthreads();

    // ---------------- Phase B1: horizontal sums -> a,b (b128 reads) ---------
    const int vr = tid >> 2;            // 0..47 (tid<192)
    const int u4 = tid & 3;             // col-block: ab cols u4*12 .. +11
    float oa[12], ob[12];
    if (tid < 192) {
        float sm[4][12];
        #pragma unroll
        for (int q = 0; q < 4; ++q) {
            float vv[28];
            #pragma unroll
            for (int t = 0; t < 7; ++t) {
                const float4 w = S4[q * PL4 + vr * 17 + u4 * 3 + t];
                vv[4 * t + 0] = w.x; vv[4 * t + 1] = w.y;
                vv[4 * t + 2] = w.z; vv[4 * t + 3] = w.w;
            }
            float s = 0.f;
            #pragma unroll
            for (int j = 0; j < 17; ++j) s += vv[j];
            sm[q][0] = s;
            #pragma unroll
            for (int o = 1; o < 12; ++o) {
                s += vv[o + 16] - vv[o - 1];
                sm[q][o] = s;
            }
        }
        #pragma unroll
        for (int o = 0; o < 12; ++o) {
            const float mI  = sm[0][o] * INV_AREA;
            const float mP  = sm[1][o] * INV_AREA;
            const float mIp = sm[2][o] * INV_AREA;
            const float mII = sm[3][o] * INV_AREA;
            const float cov = mIp - mI * mP;
            const float var = mII - mI * mI;
            const float av  = cov / (var + EPS);
            oa[o] = av;
            ob[o] = mP - av * mI;
        }
    }
    __syncthreads();
    if (tid < 192) {
        #pragma unroll
        for (int t = 0; t < 3; ++t) {
            S4[0 * PL4 + vr * 17 + u4 * 3 + t] =
                make_float4(oa[4 * t], oa[4 * t + 1], oa[4 * t + 2], oa[4 * t + 3]);
            S4[1 * PL4 + vr * 17 + u4 * 3 + t] =
                make_float4(ob[4 * t], ob[4 * t + 1], ob[4 * t + 2], ob[4 * t + 3]);
        }
    }
    __syncthreads();

    // ---------------- Phase B2: horizontal sums of a,b -> planes 2,3 --------
    if (tid < 192) {
        float va[24], vb[24];
        #pragma unroll
        for (int t = 0; t < 6; ++t) {
            const float4 wa = S4[0 * PL4 + vr * 17 + u4 * 2 + t];
            const float4 wb = S4[1 * PL4 + vr * 17 + u4 * 2 + t];
            va[4 * t + 0] = wa.x; va[4 * t + 1] = wa.y;
            va[4 * t + 2] = wa.z; va[4 * t + 3] = wa.w;
            vb[4 * t + 0] = wb.x; vb[4 * t + 1] = wb.y;
            vb[4 * t + 2] = wb.z; vb[4 * t + 3] = wb.w;
        }
        float hsA[8], hsB[8];
        float sa = 0.f, sb = 0.f;
        #pragma unroll
        for (int j = 0; j < 17; ++j) { sa += va[j]; sb += vb[j]; }
        hsA[0] = sa; hsB[0] = sb;
        #pragma unroll
        for (int o = 1; o < 8; ++o) {
            sa += va[o + 16] - va[o - 1];
            sb += vb[o + 16] - vb[o - 1];
            hsA[o] = sa; hsB[o] = sb;
        }
        #pragma unroll
        for (int t = 0; t < 2; ++t) {
            S4[2 * PL4 + vr * 17 + u4 * 2 + t] =
                make_float4(hsA[4 * t], hsA[4 * t + 1], hsA[4 * t + 2], hsA[4 * t + 3]);
            S4[3 * PL4 + vr * 17 + u4 * 2 + t] =
                make_float4(hsB[4 * t], hsB[4 * t + 1], hsB[4 * t + 2], hsB[4 * t + 3]);
        }
    }
    __syncthreads();

    // ---------------- Phase C: vertical sums + finale -----------------------
    {
        const int ox  = tid & 31;
        const int oy0 = (tid >> 5) * 4;    // 0,4,...,28
        float sa = 0.f, sb = 0.f;
        #pragma unroll
        for (int j = 0; j < 17; ++j) {
            sa += Sf[2 * PL + (oy0 + j) * STRD + ox];
            sb += Sf[3 * PL + (oy0 + j) * STRD + ox];
        }
        #pragma unroll
        for (int o = 0; o < 4; ++o) {
            if (o) {
                sa += Sf[2 * PL + (oy0 + o + 16) * STRD + ox]
                    - Sf[2 * PL + (oy0 + o - 1) * STRD + ox];
                sb += Sf[3 * PL + (oy0 + o + 16) * STRD + ox]
                    - Sf[3 * PL + (oy0 + o - 1) * STRD + ox];
            }
            const size_t gp = (size_t)(ty0 + oy0 + o) * W + (tx0 + ox);
            O[plane + gp] = sa * INV_AREA * Ic[gp] + sb * INV_AREA;
        }
    }
}

extern "C" void kernel_launch(void* const* d_in, const int* in_sizes, int n_in,
                              void* d_out, int out_size, void* d_ws, size_t ws_size,
                              hipStream_t stream) {
    const int H = 1024, W = 1024;
    if (n_in < 2) return;
    const long long npx = (long long)H * W;
    const long long n0 = in_sizes[0];
    if (n0 <= 0 || (n0 % npx) != 0) return;
    if ((long long)out_size != n0) return;
    if (in_sizes[1] != in_sizes[0]) return;
    const int NP = (int)(n0 / npx);

    const float* p = (const float*)d_in[0];   // input_img
    const float* I = (const float*)d_in[1];   // guide_img
    float* out = (float*)d_out;

    dim3 grid(W / TW, H / TH, NP);
    gf_fused<<<grid, 256, 0, stream>>>(p, I, out, H, W);
}